// Round 11
// baseline (178.157 us; speedup 1.0000x reference)
//
#include <hip/hip_runtime.h>
#include <hip/hip_bf16.h>

#define N_ROWS 8192
#define DIM 512
#define SCALE 2.659f
#define MAXLOGIT 2.659f
#define LOG2E 1.4426950408889634f
#define BM 256
#define BN 256
#define NCLS 128
#define GEMM_BLKS 1024   // (8192/256)^2

typedef __attribute__((ext_vector_type(8))) short short8;
typedef __attribute__((ext_vector_type(4))) float f32x4;

// zero region: rs(8192) + cs(8192) + c_txt(65536) + c_img(65536) + cnt(128)
#define ZERO_F4 36896

__device__ __forceinline__ unsigned short f2bf(float f) {
    unsigned int u = __float_as_uint(f);
    u += 0x7fffu + ((u >> 16) & 1u);
    return (unsigned short)(u >> 16);
}

// ---------------------------------------------------------------- normalize
__global__ __launch_bounds__(256) void norm_cast_kernel(
    const float* __restrict__ text, const float* __restrict__ image,
    const int* __restrict__ labels,
    unsigned short* __restrict__ imgn, unsigned short* __restrict__ txtn,
    float4* __restrict__ zbase, float* __restrict__ sd, float* __restrict__ out)
{
    int zi = blockIdx.x * 256 + threadIdx.x;
    if (zi < ZERO_F4) zbase[zi] = make_float4(0.f, 0.f, 0.f, 0.f);
    if (zi == 0) out[0] = 0.f;

    int row  = blockIdx.x * 4 + (threadIdx.x >> 6);
    int lane = threadIdx.x & 63;
    const float4* si = (const float4*)(image + (size_t)row * DIM) + lane * 2;
    const float4* st = (const float4*)(text  + (size_t)row * DIM) + lane * 2;
    float4 a = si[0], b = si[1], c = st[0], d = st[1];
    float ssa = a.x*a.x + a.y*a.y + a.z*a.z + a.w*a.w
              + b.x*b.x + b.y*b.y + b.z*b.z + b.w*b.w;
    float sst = c.x*c.x + c.y*c.y + c.z*c.z + c.w*c.w
              + d.x*d.x + d.y*d.y + d.z*d.z + d.w*d.w;
    float sab = a.x*c.x + a.y*c.y + a.z*c.z + a.w*c.w
              + b.x*d.x + b.y*d.y + b.z*d.z + b.w*d.w;
    #pragma unroll
    for (int m = 1; m < 64; m <<= 1) {
        ssa += __shfl_xor(ssa, m, 64);
        sst += __shfl_xor(sst, m, 64);
        sab += __shfl_xor(sab, m, 64);
    }
    float sca = 1.0f / fmaxf(sqrtf(ssa), 1e-12f);
    float sct = 1.0f / fmaxf(sqrtf(sst), 1e-12f);
    uint4 oi, ot;
    oi.x = (unsigned)f2bf(a.x*sca) | ((unsigned)f2bf(a.y*sca) << 16);
    oi.y = (unsigned)f2bf(a.z*sca) | ((unsigned)f2bf(a.w*sca) << 16);
    oi.z = (unsigned)f2bf(b.x*sca) | ((unsigned)f2bf(b.y*sca) << 16);
    oi.w = (unsigned)f2bf(b.z*sca) | ((unsigned)f2bf(b.w*sca) << 16);
    ot.x = (unsigned)f2bf(c.x*sct) | ((unsigned)f2bf(c.y*sct) << 16);
    ot.y = (unsigned)f2bf(c.z*sct) | ((unsigned)f2bf(c.w*sct) << 16);
    ot.z = (unsigned)f2bf(d.x*sct) | ((unsigned)f2bf(d.y*sct) << 16);
    ot.w = (unsigned)f2bf(d.z*sct) | ((unsigned)f2bf(d.w*sct) << 16);
    *((uint4*)(imgn + (size_t)row * DIM) + lane) = oi;
    *((uint4*)(txtn + (size_t)row * DIM) + lane) = ot;
    if (lane == 0)
        sd[row] = (labels[row] < 0) ? sab * sca * sct : 0.0f;
}

// ---------------------------------------------------------------- fused GEMM
// Blocks [0, GEMM_BLKS): 256x256 tile, faithful m201 phase rhythm:
//   per phase {ds_read frags ; stage -> s_barrier -> lgkmcnt(0)+SFENCE ->
//   setprio(1) 16 MFMA setprio(0) -> s_barrier}; counted vmcnt(2) once per
//   K-tile. Reads issued BEFORE the barrier so LDS latency fills the sync
//   slack; second barrier creates the role-split setprio arbitrates.
// Blocks [GEMM_BLKS, +256): class-sum (one block per (class, matrix)).
#define ASYNC16(gp, lp) \
  __builtin_amdgcn_global_load_lds((const __attribute__((address_space(1))) void*)(gp), \
                                   (__attribute__((address_space(3))) void*)(lp), 16, 0, 0)

#define SFENCE __builtin_amdgcn_sched_barrier(0)
#define BARRIER { SFENCE; __builtin_amdgcn_s_barrier(); SFENCE; }
#define WAITLGKM { asm volatile("s_waitcnt lgkmcnt(0)" ::: "memory"); SFENCE; }

// stage one 128-row x 64-col half-tile: each wave 2 loads (8 rows each),
// per-lane source row = +lane>>3, source k-slot pre-swizzled.
#define STG_A(db_, h_, kofs_)                                                 \
  {                                                                           \
    const unsigned short* _p = A + (size_t)(rowBase + (h_)*128 + w*16 + srow8) * DIM \
                                 + (kofs_) + swz8;                            \
    ASYNC16(_p,           &Ald[db_][h_][w*1024]);                             \
    ASYNC16(_p + 8*DIM,   &Ald[db_][h_][w*1024 + 512]);                       \
  }
#define STG_B(db_, h_, kofs_)                                                 \
  {                                                                           \
    const unsigned short* _p = B + (size_t)(colBase + (h_)*128 + w*16 + srow8) * DIM \
                                 + (kofs_) + swz8;                            \
    ASYNC16(_p,           &Bld[db_][h_][w*1024]);                             \
    ASYNC16(_p + 8*DIM,   &Bld[db_][h_][w*1024 + 512]);                       \
  }

#define LDA8(db_, kk_)                                                        \
  _Pragma("unroll")                                                           \
  for (int mi = 0; mi < 8; ++mi)                                              \
      af[mi] = *(const short8*)(&Ald[db_][wr][(mi*16 + lm)*64 +               \
                                (((kk_<<2)|q) ^ (lm & 7))*8]);
#define LDB(db_, kk_, ni_)                                                    \
  (*(const short8*)(&Bld[db_][hb][((wc&1)*64 + (ni_)*16 + lm)*64 +            \
                                  (((kk_<<2)|q) ^ (lm & 7))*8]))
#define MM2(n0_, n1_, b0_, b1_)                                               \
  {                                                                           \
    __builtin_amdgcn_s_setprio(1);                                            \
    _Pragma("unroll")                                                         \
    for (int mi = 0; mi < 8; ++mi)                                            \
        acc[mi][n0_] = __builtin_amdgcn_mfma_f32_16x16x32_bf16(af[mi], b0_, acc[mi][n0_], 0, 0, 0); \
    _Pragma("unroll")                                                         \
    for (int mi = 0; mi < 8; ++mi)                                            \
        acc[mi][n1_] = __builtin_amdgcn_mfma_f32_16x16x32_bf16(af[mi], b1_, acc[mi][n1_], 0, 0, 0); \
    __builtin_amdgcn_s_setprio(0);                                            \
  }

__global__ __launch_bounds__(512, 2) void gemm_fused_kernel(
    const unsigned short* __restrict__ imgn, const unsigned short* __restrict__ txtn,
    const int* __restrict__ labels,
    float* __restrict__ rs, float* __restrict__ cs,
    float* __restrict__ c_txt, float* __restrict__ c_img, int* __restrict__ cnt)
{
    __shared__ unsigned short Ald[2][2][128 * 64];   // 64 KB
    __shared__ unsigned short Bld[2][2][128 * 64];   // 64 KB
    __shared__ float red[4][BM];                     // 4 KB
    __shared__ float colb[2][BN];                    // 2 KB
    __shared__ int   list[1024];                     // 4 KB (class path)
    __shared__ int   lcount;

    int tid = threadIdx.x;

    // ---------------- class-sum path ----------------
    if (blockIdx.x >= GEMM_BLKS) {
        int blk = blockIdx.x - GEMM_BLKS;
        int cls = blk & (NCLS - 1);
        int mat = blk >> 7;                    // 0: txt sums, 1: img sums
        const unsigned* src = (const unsigned*)(mat ? imgn : txtn);
        float* dst = mat ? c_img : c_txt;
        if (tid == 0) lcount = 0;
        __syncthreads();
        #pragma unroll
        for (int base = 0; base < N_ROWS; base += 512) {
            int lb = labels[base + tid];
            if (lb == cls) { int s = atomicAdd(&lcount, 1); list[s & 1023] = base + tid; }
        }
        __syncthreads();
        int m = lcount;
        if (mat == 0 && tid == 0) cnt[cls] = m;
        int half = tid >> 8;                   // two thread-halves split rows
        int col  = tid & 255;                  // u32 column (2 bf16)
        float a0 = 0.f, a1 = 0.f;
        int r = half;
        for (; r + 6 < m; r += 8) {            // 4 independent loads in flight
            unsigned u0 = src[(size_t)list[r]   * (DIM/2) + col];
            unsigned u1 = src[(size_t)list[r+2] * (DIM/2) + col];
            unsigned u2 = src[(size_t)list[r+4] * (DIM/2) + col];
            unsigned u3 = src[(size_t)list[r+6] * (DIM/2) + col];
            a0 += __uint_as_float((u0 & 0xffffu) << 16) + __uint_as_float((u1 & 0xffffu) << 16)
                + __uint_as_float((u2 & 0xffffu) << 16) + __uint_as_float((u3 & 0xffffu) << 16);
            a1 += __uint_as_float(u0 & 0xffff0000u) + __uint_as_float(u1 & 0xffff0000u)
                + __uint_as_float(u2 & 0xffff0000u) + __uint_as_float(u3 & 0xffff0000u);
        }
        for (; r < m; r += 2) {
            unsigned u = src[(size_t)list[r] * (DIM/2) + col];
            a0 += __uint_as_float((u & 0xffffu) << 16);
            a1 += __uint_as_float(u & 0xffff0000u);
        }
        if (a0 != 0.f || a1 != 0.f) {
            unsafeAtomicAdd(&dst[(size_t)cls * DIM + col*2],     a0);
            unsafeAtomicAdd(&dst[(size_t)cls * DIM + col*2 + 1], a1);
        }
        return;
    }

    // ---------------- GEMM path ----------------
    int bid    = blockIdx.x;
    int rowblk = bid & 31;
    int colblk = bid >> 5;        // consecutive bids share colblk -> B L2-hot
    const unsigned short* A = imgn;
    const unsigned short* B = txtn;
    int rowBase = rowblk * BM;
    int colBase = colblk * BN;

    int lane = tid & 63;
    int w    = tid >> 6;          // 0..7
    int wr   = w >> 2;            // A half (rows wr*128..)
    int wc   = w & 3;             // col quarter (cols wc*64..)
    int hb   = wc >> 1;           // B half
    int q    = lane >> 4;
    int lm   = lane & 15;

    int srow8 = lane >> 3;                              // row within 8-row chunk
    int swz8  = (((lane & 7) ^ ((lane >> 3) & 7)) * 8); // pre-swizzled src slot

    const float C1 = SCALE * LOG2E;
    const float C2 = -MAXLOGIT * LOG2E;

    f32x4 acc[8][4];
    #pragma unroll
    for (int mi = 0; mi < 8; ++mi)
      #pragma unroll
      for (int ni = 0; ni < 4; ++ni)
        acc[mi][ni] = (f32x4){0.f, 0.f, 0.f, 0.f};

    // prologue: tile0 fully + A_h0(1); drain once.
    STG_A(0, 0, 0);
    STG_A(0, 1, 0);
    STG_B(0, 0, 0);
    STG_B(0, 1, 0);
    STG_A(1, 0, 64);
    SFENCE;
    asm volatile("s_waitcnt vmcnt(0)" ::: "memory");
    BARRIER;

    short8 af[8];

    #pragma unroll
    for (int t = 0; t < DIM / 64; ++t) {       // 8 K-tiles
        const int db = t & 1;
        const int dn = (t + 1) & 1;
        const int k0 = t * 64;
        short8 b0, b1, b2, b3;

        // ---- phase 0: reads (A kk0 + B n0,n1 kk0) ; stage A_h1/B_h0(t+1)
        LDA8(db, 0);
        b0 = LDB(db, 0, 0); b1 = LDB(db, 0, 1);
        if (t + 1 < 8) { STG_A(dn, 1, k0 + 64); STG_B(dn, 0, k0 + 64); }
        BARRIER;
        WAITLGKM;
        MM2(0, 1, b0, b1);
        BARRIER;

        // ---- phase 1: reads (B n2,n3 kk0) ; stage B_h1(t+1)
        b2 = LDB(db, 0, 2); b3 = LDB(db, 0, 3);
        if (t + 1 < 8) STG_B(dn, 1, k0 + 64);
        BARRIER;
        WAITLGKM;
        MM2(2, 3, b2, b3);
        BARRIER;

        // ---- phase 2: reads (A kk1 + B n0,n1 kk1)
        LDA8(db, 1);
        b0 = LDB(db, 1, 0); b1 = LDB(db, 1, 1);
        BARRIER;
        WAITLGKM;
        MM2(0, 1, b0, b1);
        BARRIER;

        // ---- phase 3: reads (B n2,n3 kk1) ; stage A_h0(t+2)
        b2 = LDB(db, 1, 2); b3 = LDB(db, 1, 3);
        if (t + 2 < 8) STG_A(db, 0, k0 + 128);
        BARRIER;
        WAITLGKM;
        MM2(2, 3, b2, b3);
        // tile boundary: allow only A_h0(t+2)'s 2 loads outstanding =>
        // A(t+1)/B(t+1) (staged ph3(t-1), ph0, ph1) have landed.
        SFENCE;
        if (t < 6) asm volatile("s_waitcnt vmcnt(2)" ::: "memory");
        else       asm volatile("s_waitcnt vmcnt(0)" ::: "memory");
        BARRIER;
    }

    // epilogue (round-8 verified geometry): one exp serves both directions.
    float rsum[32];
    #pragma unroll
    for (int i = 0; i < 32; ++i) rsum[i] = 0.f;
    #pragma unroll
    for (int ni = 0; ni < 4; ++ni) {
        float csum = 0.f;
        #pragma unroll
        for (int mi = 0; mi < 8; ++mi) {
          #pragma unroll
          for (int r = 0; r < 4; ++r) {
            float e = __builtin_amdgcn_exp2f(fmaf(acc[mi][ni][r], C1, C2));
            rsum[mi*4 + r] += e;
            csum += e;
          }
        }
        csum += __shfl_xor(csum, 16, 64);      // reduce over q
        csum += __shfl_xor(csum, 32, 64);
        if (q == 0)
            colb[wr][wc*64 + ni*16 + lm] = csum;
    }
    #pragma unroll
    for (int idx = 0; idx < 32; ++idx) {
        float s = rsum[idx];
        #pragma unroll
        for (int m = 1; m < 16; m <<= 1) s += __shfl_xor(s, m, 64);
        if (lm == 0)
            red[wc][wr*128 + (idx>>2)*16 + q*4 + (idx&3)] = s;
    }
    __syncthreads();
    if (tid < BM) {
        unsafeAtomicAdd(&rs[rowBase + tid],
                        red[0][tid] + red[1][tid] + red[2][tid] + red[3][tid]);
        unsafeAtomicAdd(&cs[colBase + tid], colb[0][tid] + colb[1][tid]);
    }
}

// ---------------------------------------------------------------- final loss
__global__ __launch_bounds__(256) void loss_tail_kernel(
    const float* __restrict__ rs, const float* __restrict__ cs,
    const float* __restrict__ sd, const float* __restrict__ c_txt,
    const float* __restrict__ c_img, const int* __restrict__ cnt,
    float* __restrict__ out)
{
    __shared__ float wsum[4];
    int tid = threadIdx.x, lane = tid & 63, w = tid >> 6;
    int gidx = blockIdx.x * 256 + tid;           // 0..16383
    float local;
    if (gidx < N_ROWS)
        local = (MAXLOGIT + logf(rs[gidx])) - 2.0f * SCALE * sd[gidx];
    else
        local = MAXLOGIT + logf(cs[gidx - N_ROWS]);

    int cls = blockIdx.x * 2 + (tid >> 7);       // 0..127
    int e0  = (tid & 127) * 4;
    int n   = cnt[cls];
    if (n > 0) {
        float4 x = *(const float4*)(c_txt + (size_t)cls * DIM + e0);
        float4 y = *(const float4*)(c_img + (size_t)cls * DIM + e0);
        float dotp = x.x*y.x + x.y*y.y + x.z*y.z + x.w*y.w;
        local -= 2.0f * SCALE * dotp / (float)n;
    }

    #pragma unroll
    for (int m = 1; m < 64; m <<= 1) local += __shfl_xor(local, m, 64);
    if (lane == 0) wsum[w] = local;
    __syncthreads();
    if (tid == 0)
        unsafeAtomicAdd(out, (wsum[0] + wsum[1] + wsum[2] + wsum[3])
                             * (1.0f / (2 * N_ROWS)));
}

// ---------------------------------------------------------------- launch
extern "C" void kernel_launch(void* const* d_in, const int* in_sizes, int n_in,
                              void* d_out, int out_size, void* d_ws, size_t ws_size,
                              hipStream_t stream)
{
    const float* text   = (const float*)d_in[0];
    const float* image  = (const float*)d_in[1];
    const int*   labels = (const int*)d_in[2];

    unsigned short* imgn = (unsigned short*)d_ws;
    unsigned short* txtn = imgn + (size_t)N_ROWS * DIM;
    char* p = (char*)d_ws + 2 * (size_t)N_ROWS * DIM * sizeof(unsigned short);
    float* rs    = (float*)p;                       // 8192 f32  (zeroed)
    float* cs    = rs + N_ROWS;                     // 8192 f32  (zeroed)
    float* c_txt = cs + N_ROWS;                     // 128*512 f32 (zeroed)
    float* c_img = c_txt + (size_t)NCLS * DIM;      // 128*512 f32 (zeroed)
    int*   cnt   = (int*)(c_img + (size_t)NCLS * DIM); // 128 (zeroed)
    float* sd    = (float*)(cnt + NCLS);            // 8192 f32 (fully written)
    float* out = (float*)d_out;

    hipLaunchKernelGGL(norm_cast_kernel, dim3(N_ROWS / 4), dim3(256), 0, stream,
                       text, image, labels, imgn, txtn, (float4*)rs, sd, out);
    hipLaunchKernelGGL(gemm_fused_kernel, dim3(GEMM_BLKS + 2 * NCLS), dim3(512), 0, stream,
                       imgn, txtn, labels, rs, cs, c_txt, c_img, cnt);
    hipLaunchKernelGGL(loss_tail_kernel, dim3(64), dim3(256), 0, stream,
                       rs, cs, sd, c_txt, c_img, cnt, out);
}

// Round 12
// 172.910 us; speedup vs baseline: 1.0303x; 1.0303x over previous
//
#include <hip/hip_runtime.h>
#include <hip/hip_bf16.h>

#define N_ROWS 8192
#define DIM 512
#define SCALE 2.659f
#define MAXLOGIT 2.659f
#define LOG2E 1.4426950408889634f
#define BM 256
#define BN 128
#define NCLS 128
#define GEMM_BLKS 2048   // 32 rowblks x 64 colblks

typedef __attribute__((ext_vector_type(8))) short short8;
typedef __attribute__((ext_vector_type(4))) float f32x4;

// zero region: rs(8192) + cs(8192) + c_txt(65536) + c_img(65536) + cnt(128)
#define ZERO_F4 36896

__device__ __forceinline__ unsigned short f2bf(float f) {
    unsigned int u = __float_as_uint(f);
    u += 0x7fffu + ((u >> 16) & 1u);
    return (unsigned short)(u >> 16);
}

// ---------------------------------------------------------------- normalize
__global__ __launch_bounds__(256) void norm_cast_kernel(
    const float* __restrict__ text, const float* __restrict__ image,
    const int* __restrict__ labels,
    unsigned short* __restrict__ imgn, unsigned short* __restrict__ txtn,
    float4* __restrict__ zbase, float* __restrict__ sd, float* __restrict__ out)
{
    int zi = blockIdx.x * 256 + threadIdx.x;
    if (zi < ZERO_F4) zbase[zi] = make_float4(0.f, 0.f, 0.f, 0.f);
    if (zi == 0) out[0] = 0.f;

    int row  = blockIdx.x * 4 + (threadIdx.x >> 6);
    int lane = threadIdx.x & 63;
    const float4* si = (const float4*)(image + (size_t)row * DIM) + lane * 2;
    const float4* st = (const float4*)(text  + (size_t)row * DIM) + lane * 2;
    float4 a = si[0], b = si[1], c = st[0], d = st[1];
    float ssa = a.x*a.x + a.y*a.y + a.z*a.z + a.w*a.w
              + b.x*b.x + b.y*b.y + b.z*b.z + b.w*b.w;
    float sst = c.x*c.x + c.y*c.y + c.z*c.z + c.w*c.w
              + d.x*d.x + d.y*d.y + d.z*d.z + d.w*d.w;
    float sab = a.x*c.x + a.y*c.y + a.z*c.z + a.w*c.w
              + b.x*d.x + b.y*d.y + b.z*d.z + b.w*d.w;
    #pragma unroll
    for (int m = 1; m < 64; m <<= 1) {
        ssa += __shfl_xor(ssa, m, 64);
        sst += __shfl_xor(sst, m, 64);
        sab += __shfl_xor(sab, m, 64);
    }
    float sca = 1.0f / fmaxf(sqrtf(ssa), 1e-12f);
    float sct = 1.0f / fmaxf(sqrtf(sst), 1e-12f);
    uint4 oi, ot;
    oi.x = (unsigned)f2bf(a.x*sca) | ((unsigned)f2bf(a.y*sca) << 16);
    oi.y = (unsigned)f2bf(a.z*sca) | ((unsigned)f2bf(a.w*sca) << 16);
    oi.z = (unsigned)f2bf(b.x*sca) | ((unsigned)f2bf(b.y*sca) << 16);
    oi.w = (unsigned)f2bf(b.z*sca) | ((unsigned)f2bf(b.w*sca) << 16);
    ot.x = (unsigned)f2bf(c.x*sct) | ((unsigned)f2bf(c.y*sct) << 16);
    ot.y = (unsigned)f2bf(c.z*sct) | ((unsigned)f2bf(c.w*sct) << 16);
    ot.z = (unsigned)f2bf(d.x*sct) | ((unsigned)f2bf(d.y*sct) << 16);
    ot.w = (unsigned)f2bf(d.z*sct) | ((unsigned)f2bf(d.w*sct) << 16);
    *((uint4*)(imgn + (size_t)row * DIM) + lane) = oi;
    *((uint4*)(txtn + (size_t)row * DIM) + lane) = ot;
    if (lane == 0)
        sd[row] = (labels[row] < 0) ? sab * sca * sct : 0.0f;
}

// ---------------------------------------------------------------- fused GEMM
// Blocks [0, GEMM_BLKS): 256x128 output tile, NO tile loop, 16 K-steps.
//   Round-7-verified sync skeleton: 3 LDS buffers (index = g%3, static after
//   full unroll), depth-2 prefetch, step-end counted s_waitcnt vmcnt(6)
//   (= the 6 loads of stage(g+2)) then s_barrier; tail drains. 4 waves
//   (2Mx2N), per-wave 128x64 -> 32 MFMA per barrier (2x round 9).
// Blocks [GEMM_BLKS, +2048): class-sum (8 slices x 128 cls x 2 mats).
// Swizzle (round-9 verified, conflicts=0): pre-swizzled global src k-chunk
//   (lane&3)^((lane>>3)&3), linear LDS dest; read slot q^((lm>>1)&3).
#define ASYNC16(gp, lp) \
  __builtin_amdgcn_global_load_lds((const __attribute__((address_space(1))) void*)(gp), \
                                   (__attribute__((address_space(3))) void*)(lp), 16, 0, 0)

#define SFENCE __builtin_amdgcn_sched_barrier(0)

// stage one 256x32 A-slice (4 loads) + 128x32 B-slice (2 loads) per thread.
#define STAGE(b, k0)                                                          \
  {                                                                           \
    const unsigned short* Ap = A + (size_t)(rowBase + w*16 + srow) * DIM      \
                                 + (k0) + spsw;                               \
    const unsigned short* Bp = B + (size_t)(colBase + w*16 + srow) * DIM      \
                                 + (k0) + spsw;                               \
    ASYNC16(Ap,             &Ald[b][(w*16) * 32]);                            \
    ASYNC16(Ap +  64 * DIM, &Ald[b][( 64 + w*16) * 32]);                      \
    ASYNC16(Ap + 128 * DIM, &Ald[b][(128 + w*16) * 32]);                      \
    ASYNC16(Ap + 192 * DIM, &Ald[b][(192 + w*16) * 32]);                      \
    ASYNC16(Bp,             &Bld[b][(w*16) * 32]);                            \
    ASYNC16(Bp +  64 * DIM, &Bld[b][( 64 + w*16) * 32]);                      \
  }

__global__ __launch_bounds__(256, 2) void gemm_fused_kernel(
    const unsigned short* __restrict__ imgn, const unsigned short* __restrict__ txtn,
    const int* __restrict__ labels,
    float* __restrict__ rs, float* __restrict__ cs,
    float* __restrict__ c_txt, float* __restrict__ c_img, int* __restrict__ cnt)
{
    __shared__ unsigned short Ald[3][BM * 32];   // 48 KB
    __shared__ unsigned short Bld[3][BN * 32];   // 24 KB
    __shared__ float red[2][BM];                 // 2 KB  [wc][row-in-tile]
    __shared__ float colb[2][BN];                // 1 KB  [wr][col-in-tile]
    __shared__ int   list[1024];                 // 4 KB  (class path)
    __shared__ int   lcount;

    int tid = threadIdx.x;

    // ---------------- class-sum path ----------------
    if (blockIdx.x >= GEMM_BLKS) {
        int blk = blockIdx.x - GEMM_BLKS;
        int cls = blk & (NCLS - 1);
        int mat = (blk >> 7) & 1;              // 0: txt sums, 1: img sums
        int slc = blk >> 8;                    // 0..7
        const unsigned* src = (const unsigned*)(mat ? imgn : txtn);
        float* dst = mat ? c_img : c_txt;
        if (tid == 0) lcount = 0;
        __syncthreads();
        int base0 = slc * 1024;
        #pragma unroll
        for (int it = 0; it < 4; ++it) {
            int i  = base0 + it * 256 + tid;
            int lb = labels[i];
            if (lb == cls) { int s = atomicAdd(&lcount, 1); list[s & 1023] = i; }
        }
        __syncthreads();
        int m = lcount;
        if (m == 0) return;
        if (mat == 0 && tid == 0) atomicAdd(&cnt[cls], m);
        float a0 = 0.f, a1 = 0.f;
        int r = 0;
        for (; r + 4 <= m; r += 4) {           // 4 independent loads in flight
            unsigned u0 = src[(size_t)list[r]   * (DIM/2) + tid];
            unsigned u1 = src[(size_t)list[r+1] * (DIM/2) + tid];
            unsigned u2 = src[(size_t)list[r+2] * (DIM/2) + tid];
            unsigned u3 = src[(size_t)list[r+3] * (DIM/2) + tid];
            a0 += __uint_as_float((u0 & 0xffffu) << 16) + __uint_as_float((u1 & 0xffffu) << 16)
                + __uint_as_float((u2 & 0xffffu) << 16) + __uint_as_float((u3 & 0xffffu) << 16);
            a1 += __uint_as_float(u0 & 0xffff0000u) + __uint_as_float(u1 & 0xffff0000u)
                + __uint_as_float(u2 & 0xffff0000u) + __uint_as_float(u3 & 0xffff0000u);
        }
        for (; r < m; ++r) {
            unsigned u = src[(size_t)list[r] * (DIM/2) + tid];
            a0 += __uint_as_float((u & 0xffffu) << 16);
            a1 += __uint_as_float(u & 0xffff0000u);
        }
        unsafeAtomicAdd(&dst[(size_t)cls * DIM + tid*2],     a0);
        unsafeAtomicAdd(&dst[(size_t)cls * DIM + tid*2 + 1], a1);
        return;
    }

    // ---------------- GEMM path ----------------
    int bid    = blockIdx.x;
    int rowblk = bid & 31;
    int colblk = bid >> 5;        // 32 consecutive bids share the B panel
    const unsigned short* A = imgn;
    const unsigned short* B = txtn;
    int rowBase = rowblk * BM;
    int colBase = colblk * BN;

    int lane = tid & 63;
    int w    = tid >> 6;          // 0..3
    int wr   = w >> 1;            // row half: rows wr*128..
    int wc   = w & 1;             // col half: cols wc*64..
    int q    = lane >> 4;
    int lm   = lane & 15;
    int qa   = q ^ ((lm >> 1) & 3);   // swizzled read slot

    int srow = lane >> 2;                               // staging row in group
    int spsw = (((lane & 3) ^ ((lane >> 3) & 3)) * 8);  // swizzled src k-chunk

    const float C1 = SCALE * LOG2E;
    const float C2 = -MAXLOGIT * LOG2E;

    f32x4 acc[8][4];
    #pragma unroll
    for (int mi = 0; mi < 8; ++mi)
      #pragma unroll
      for (int ni = 0; ni < 4; ++ni)
        acc[mi][ni] = (f32x4){0.f, 0.f, 0.f, 0.f};

    // prologue: stage step 0 -> buf0, step 1 -> buf1; wait only for step 0.
    STAGE(0, 0);
    STAGE(1, 32);
    SFENCE;
    asm volatile("s_waitcnt vmcnt(6)" ::: "memory");
    SFENCE;
    __builtin_amdgcn_s_barrier();
    SFENCE;

    #pragma unroll
    for (int g = 0; g < DIM / 32; ++g) {       // 16 K-steps, one output tile
        const int bcur = g % 3;                // static after full unroll
        const int bpf  = (g + 2) % 3;
        if (g + 2 < DIM / 32) {
            STAGE(bpf, (g + 2) * 32);          // depth-2 prefetch
        }

        short8 af[8], bf[4];
        #pragma unroll
        for (int mi = 0; mi < 8; ++mi)
            af[mi] = *(const short8*)(&Ald[bcur][(wr*128 + mi*16 + lm)*32 + qa*8]);
        #pragma unroll
        for (int ni = 0; ni < 4; ++ni)
            bf[ni] = *(const short8*)(&Bld[bcur][(wc*64 + ni*16 + lm)*32 + qa*8]);
        #pragma unroll
        for (int mi = 0; mi < 8; ++mi)
          #pragma unroll
          for (int ni = 0; ni < 4; ++ni)
            acc[mi][ni] = __builtin_amdgcn_mfma_f32_16x16x32_bf16(
                              af[mi], bf[ni], acc[mi][ni], 0, 0, 0);

        // counted wait: the 6 newest outstanding loads are stage(g+2);
        // <=6 outstanding => stage(g+1) landed. Then barrier => all waves'
        // stage(g+1) landed before anyone enters step g+1. Tail drains.
        SFENCE;
        if (g + 2 < DIM / 32) asm volatile("s_waitcnt vmcnt(6)" ::: "memory");
        else                  asm volatile("s_waitcnt vmcnt(0)" ::: "memory");
        SFENCE;
        __builtin_amdgcn_s_barrier();
        SFENCE;
    }

    // epilogue: one exp per S element serves BOTH loss directions.
    float rsum[32];
    #pragma unroll
    for (int i = 0; i < 32; ++i) rsum[i] = 0.f;
    #pragma unroll
    for (int ni = 0; ni < 4; ++ni) {
        float csum = 0.f;
        #pragma unroll
        for (int mi = 0; mi < 8; ++mi) {
          #pragma unroll
          for (int r = 0; r < 4; ++r) {
            float e = __builtin_amdgcn_exp2f(fmaf(acc[mi][ni][r], C1, C2));
            rsum[mi*4 + r] += e;
            csum += e;
          }
        }
        csum += __shfl_xor(csum, 16, 64);      // reduce over q (lane bits 4,5)
        csum += __shfl_xor(csum, 32, 64);
        if (q == 0)
            colb[wr][wc*64 + ni*16 + lm] = csum;
    }
    // row sums: reduce across the 16 column-lanes (low 4 lane bits)
    #pragma unroll
    for (int idx = 0; idx < 32; ++idx) {
        float s = rsum[idx];
        #pragma unroll
        for (int m = 1; m < 16; m <<= 1) s += __shfl_xor(s, m, 64);
        if (lm == 0)
            red[wc][wr*128 + (idx>>2)*16 + q*4 + (idx&3)] = s;
    }
    __syncthreads();
    unsafeAtomicAdd(&rs[rowBase + tid], red[0][tid] + red[1][tid]);
    if (tid < BN)
        unsafeAtomicAdd(&cs[colBase + tid], colb[0][tid] + colb[1][tid]);
}

// ---------------------------------------------------------------- final loss
// loss*2N = Sum_i (M + log rs_i) + Sum_i (M + log cs_i)
//           - 2*scale*[ Sum_l <c_img[l],c_txt[l]>/cnt_l + Sum_{lab=-1} <a_i,b_i> ]
__global__ __launch_bounds__(256) void loss_tail_kernel(
    const float* __restrict__ rs, const float* __restrict__ cs,
    const float* __restrict__ sd, const float* __restrict__ c_txt,
    const float* __restrict__ c_img, const int* __restrict__ cnt,
    float* __restrict__ out)
{
    __shared__ float wsum[4];
    int tid = threadIdx.x, lane = tid & 63, w = tid >> 6;
    int gidx = blockIdx.x * 256 + tid;           // 0..16383
    float local;
    if (gidx < N_ROWS)
        local = (MAXLOGIT + logf(rs[gidx])) - 2.0f * SCALE * sd[gidx];
    else
        local = MAXLOGIT + logf(cs[gidx - N_ROWS]);

    int cls = blockIdx.x * 2 + (tid >> 7);       // 0..127
    int e0  = (tid & 127) * 4;
    int n   = cnt[cls];
    if (n > 0) {
        float4 x = *(const float4*)(c_txt + (size_t)cls * DIM + e0);
        float4 y = *(const float4*)(c_img + (size_t)cls * DIM + e0);
        float dotp = x.x*y.x + x.y*y.y + x.z*y.z + x.w*y.w;
        local -= 2.0f * SCALE * dotp / (float)n;
    }

    #pragma unroll
    for (int m = 1; m < 64; m <<= 1) local += __shfl_xor(local, m, 64);
    if (lane == 0) wsum[w] = local;
    __syncthreads();
    if (tid == 0)
        unsafeAtomicAdd(out, (wsum[0] + wsum[1] + wsum[2] + wsum[3])
                             * (1.0f / (2 * N_ROWS)));
}

// ---------------------------------------------------------------- launch
extern "C" void kernel_launch(void* const* d_in, const int* in_sizes, int n_in,
                              void* d_out, int out_size, void* d_ws, size_t ws_size,
                              hipStream_t stream)
{
    const float* text   = (const float*)d_in[0];
    const float* image  = (const float*)d_in[1];
    const int*   labels = (const int*)d_in[2];

    unsigned short* imgn = (unsigned short*)d_ws;
    unsigned short* txtn = imgn + (size_t)N_ROWS * DIM;
    char* p = (char*)d_ws + 2 * (size_t)N_ROWS * DIM * sizeof(unsigned short);
    float* rs    = (float*)p;                       // 8192 f32  (zeroed)
    float* cs    = rs + N_ROWS;                     // 8192 f32  (zeroed)
    float* c_txt = cs + N_ROWS;                     // 128*512 f32 (zeroed)
    float* c_img = c_txt + (size_t)NCLS * DIM;      // 128*512 f32 (zeroed)
    int*   cnt   = (int*)(c_img + (size_t)NCLS * DIM); // 128 (zeroed)
    float* sd    = (float*)(cnt + NCLS);            // 8192 f32 (fully written)
    float* out = (float*)d_out;

    hipLaunchKernelGGL(norm_cast_kernel, dim3(N_ROWS / 4), dim3(256), 0, stream,
                       text, image, labels, imgn, txtn, (float4*)rs, sd, out);
    hipLaunchKernelGGL(gemm_fused_kernel, dim3(GEMM_BLKS + 2048), dim3(256), 0, stream,
                       imgn, txtn, labels, rs, cs, c_txt, c_img, cnt);
    hipLaunchKernelGGL(loss_tail_kernel, dim3(64), dim3(256), 0, stream,
                       rs, cs, sd, c_txt, c_img, cnt, out);
}